// Round 1
// 528.278 us; speedup vs baseline: 1.0155x; 1.0155x over previous
//
#include <hip/hip_runtime.h>
#include <hip/hip_bf16.h>
#include <stdint.h>

// F8Linear: y[m,n] = sum_k x[m,k] * (w_f8[n,k] * s) + bias[n]
// M=1024, N=14336, K=4096.
// R9: GEMM rewritten as 256x256 8-phase schedule (guide §5 template):
//   512 thr / 8 waves (2Mx4N, half-interleaved), BK=64, 128 KiB LDS
//   (2 dbuf x 2 halves x 128x64 x {A,B}), counted vmcnt(4) per K-tile
//   (never 0 in steady state), raw s_barrier + lgkmcnt(0)+sched_barrier,
//   setprio(1) around MFMA clusters. XOR-16B-group swizzle kept
//   (measured 0 bank conflicts). Grid 224 = 8 XCD x (7 N-panels x 4 M).
// cvt_w / cvt_x / detect / fallback unchanged from R8.

#define IN_F   4096
#define OUT_F  14336
#define M_TOT  1024

// legacy fallback tile params
#define BM 128
#define BN 128

// 8-phase kernel params
#define TM 256
#define TN 256
#define TK 64
#define KT8 (IN_F / TK)   // 64

typedef __bf16  bf16x8 __attribute__((ext_vector_type(8)));
typedef __bf16  bf16x4 __attribute__((ext_vector_type(4)));
typedef float   f32x4  __attribute__((ext_vector_type(4)));

__device__ __forceinline__ void async_copy16(const void* g, void* l) {
    __builtin_amdgcn_global_load_lds(
        (const __attribute__((address_space(1))) void*)g,
        (__attribute__((address_space(3))) void*)l,
        16, 0, 0);
}

// ---- detector: bf16-valued f32 words have low16 == 0 over 1024 dwords ----
__global__ void detect_x_dtype(const uint32_t* __restrict__ xb,
                               int* __restrict__ flag) {
    __shared__ int any_low;
    if (threadIdx.x == 0) any_low = 0;
    __syncthreads();
    uint32_t bad = 0;
    for (int i = threadIdx.x; i < 1024; i += 256) bad |= (xb[i] & 0xFFFFu);
    if (bad) atomicOr(&any_low, 1);
    __syncthreads();
    if (threadIdx.x == 0) *flag = (any_low == 0) ? 1 : 0;
}

// ---- cvt_w: 58,720,256 f32 -> bf16. vec8 granule: 7,340,032 iters. ----
__global__ __launch_bounds__(256) void cvt_w_kernel(
    const f32x4* __restrict__ in, bf16x8* __restrict__ out) {
    const int stride = 3584 * 256;
    for (int i = blockIdx.x * 256 + threadIdx.x; i < 7340032; i += stride) {
        f32x4 a = in[2 * i];
        f32x4 b = in[2 * i + 1];
        bf16x8 o;
        o[0] = (__bf16)a[0]; o[1] = (__bf16)a[1];
        o[2] = (__bf16)a[2]; o[3] = (__bf16)a[3];
        o[4] = (__bf16)b[0]; o[5] = (__bf16)b[1];
        o[6] = (__bf16)b[2]; o[7] = (__bf16)b[3];
        out[i] = o;
    }
}

// ---- cvt_x: 4,194,304 elems -> bf16 (cvt f32-world, copy bf16-world) ----
__global__ __launch_bounds__(256) void cvt_x_kernel(
    const void* __restrict__ xraw, bf16x8* __restrict__ out,
    const int* __restrict__ flag) {
    const int f32w = (*flag != 0);
    const int i = blockIdx.x * 256 + threadIdx.x;   // 0..524287
    if (f32w) {
        const f32x4* in = (const f32x4*)xraw;
        f32x4 a = in[2 * i];
        f32x4 b = in[2 * i + 1];
        bf16x8 o;
        o[0] = (__bf16)a[0]; o[1] = (__bf16)a[1];
        o[2] = (__bf16)a[2]; o[3] = (__bf16)a[3];
        o[4] = (__bf16)b[0]; o[5] = (__bf16)b[1];
        o[6] = (__bf16)b[2]; o[7] = (__bf16)b[3];
        out[i] = o;
    } else {
        out[i] = ((const bf16x8*)xraw)[i];
    }
}

// ---- main GEMM: 256x256 tile, 8-phase pipelined schedule ----
__global__ __launch_bounds__(512, 2) void gemm_bf16_8ph(
    const __bf16* __restrict__ xb,     // [M_TOT][IN_F] bf16 (ws)
    const __bf16* __restrict__ wb,     // [OUT_F][IN_F] bf16 (ws)
    const float*  __restrict__ w_scale,
    const float*  __restrict__ bias,
    void*         __restrict__ yraw,   // f32 or bf16 container per flag
    const int*    __restrict__ flag_p)
{
    // [dbuf][half]: half = 128 rows x 64 cols bf16 = 16 KiB. Total 128 KiB.
    __shared__ __align__(16) __bf16 As[2][2][128 * TK];
    __shared__ __align__(16) __bf16 Bs[2][2][128 * TK];

    const int f32w = (*flag_p != 0);
    const int t    = threadIdx.x;
    const int lane = t & 63;
    const int wv   = t >> 6;     // 0..7
    const int wm   = wv >> 2;    // 0..1
    const int wn   = wv & 3;     // 0..3
    const int lidx = lane & 15;
    const int q    = lane >> 4;

    // 224 blocks = 8 XCDs x 28; per XCD: 7 N-panels x 4 M-tiles (M fastest)
    const int flat = blockIdx.x;
    const int xcd  = flat & 7;
    const int slot = flat >> 3;            // 0..27
    const int ni   = xcd * 7 + (slot >> 2);
    const int mi   = slot & 3;
    const int m0   = mi * TM;
    const int n0   = ni * TN;

    const float scale = w_scale[0];

    const __bf16* gA = xb + (size_t)m0 * IN_F;
    const __bf16* gB = wb + (size_t)n0 * IN_F;

    // staging: half-tile = 1024 slots of 16B; 512 threads x 2 loads.
    // slot s -> row = s>>3, phys 16B-group = s&7 holds LOGICAL group
    // (s&7)^(row&7)  (conflict-free swizzle; LDS dest stays linear).
    int srow[2], scgl[2];
    #pragma unroll
    for (int i = 0; i < 2; ++i) {
        const int s = i * 512 + t;
        srow[i] = s >> 3;
        scgl[i] = (s & 7) ^ (srow[i] & 7);
    }

    // ds_read byte offsets within one half-buffer (row*128B + physgrp*16B).
    // A frag rows: qm*32 + wm*16 + lidx ; B frag rows: qn*64 + wn*16 + lidx.
    int aoff[4][2], boff[2][2];
    #pragma unroll
    for (int qm = 0; qm < 4; ++qm) {
        const int row = qm * 32 + wm * 16 + lidx;
        #pragma unroll
        for (int kg = 0; kg < 2; ++kg)
            aoff[qm][kg] = row * 128 + (((kg * 4 + q) ^ (row & 7)) * 16);
    }
    #pragma unroll
    for (int qn = 0; qn < 2; ++qn) {
        const int row = qn * 64 + wn * 16 + lidx;
        #pragma unroll
        for (int kg = 0; kg < 2; ++kg)
            boff[qn][kg] = row * 128 + (((kg * 4 + q) ^ (row & 7)) * 16);
    }

    const f32x4 zero4 = {0.f, 0.f, 0.f, 0.f};
    f32x4 acc[8][4];
    #pragma unroll
    for (int i = 0; i < 8; ++i)
        #pragma unroll
        for (int j = 0; j < 4; ++j)
            acc[i][j] = zero4;

    bf16x8 areg[4][2], breg[2][2];

#define STAGE_A(tile, half) do {                                              \
    __bf16* _dst = &As[(tile) & 1][(half)][0];                                \
    const __bf16* _src = gA + (size_t)(half) * 128 * IN_F + (tile) * TK;      \
    async_copy16(_src + (size_t)srow[0] * IN_F + scgl[0] * 8, _dst + t * 8);  \
    async_copy16(_src + (size_t)srow[1] * IN_F + scgl[1] * 8,                 \
                 _dst + (512 + t) * 8);                                       \
} while (0)

#define STAGE_B(tile, half) do {                                              \
    __bf16* _dst = &Bs[(tile) & 1][(half)][0];                                \
    const __bf16* _src = gB + (size_t)(half) * 128 * IN_F + (tile) * TK;      \
    async_copy16(_src + (size_t)srow[0] * IN_F + scgl[0] * 8, _dst + t * 8);  \
    async_copy16(_src + (size_t)srow[1] * IN_F + scgl[1] * 8,                 \
                 _dst + (512 + t) * 8);                                       \
} while (0)

#define LOAD_A(base) do {                                                     \
    _Pragma("unroll")                                                         \
    for (int _qm = 0; _qm < 4; ++_qm) {                                       \
        areg[_qm][0] = *(const bf16x8*)((base) + aoff[_qm][0]);               \
        areg[_qm][1] = *(const bf16x8*)((base) + aoff[_qm][1]);               \
    }                                                                         \
} while (0)

#define LOAD_B(base) do {                                                     \
    _Pragma("unroll")                                                         \
    for (int _qn = 0; _qn < 2; ++_qn) {                                       \
        breg[_qn][0] = *(const bf16x8*)((base) + boff[_qn][0]);               \
        breg[_qn][1] = *(const bf16x8*)((base) + boff[_qn][1]);               \
    }                                                                         \
} while (0)

#define MFMA16(MO, NO) do {                                                   \
    __builtin_amdgcn_s_setprio(1);                                            \
    _Pragma("unroll")                                                         \
    for (int _qm = 0; _qm < 4; ++_qm)                                         \
        _Pragma("unroll")                                                     \
        for (int _qn = 0; _qn < 2; ++_qn) {                                   \
            acc[(MO) + _qm][(NO) + _qn] =                                     \
                __builtin_amdgcn_mfma_f32_16x16x32_bf16(                      \
                    areg[_qm][0], breg[_qn][0], acc[(MO) + _qm][(NO) + _qn],  \
                    0, 0, 0);                                                 \
            acc[(MO) + _qm][(NO) + _qn] =                                     \
                __builtin_amdgcn_mfma_f32_16x16x32_bf16(                      \
                    areg[_qm][1], breg[_qn][1], acc[(MO) + _qm][(NO) + _qn],  \
                    0, 0, 0);                                                 \
        }                                                                     \
    __builtin_amdgcn_s_setprio(0);                                            \
} while (0)

#define BARR() __builtin_amdgcn_s_barrier()
#define LGKM0() do {                                                          \
    asm volatile("s_waitcnt lgkmcnt(0)" ::: "memory");                        \
    __builtin_amdgcn_sched_barrier(0);                                        \
} while (0)

    // prologue: virtual steady-state issue order
    // [t=-2 ph3,ph4]: Ah0(0), Bh1(0)   [t=-1 ph1..ph4]: Bh0(0), Ah1(0), Ah0(1), Bh1(1)
    STAGE_A(0, 0); STAGE_B(0, 1); STAGE_B(0, 0); STAGE_A(0, 1);
    STAGE_A(1, 0); STAGE_B(1, 1);
    asm volatile("s_waitcnt vmcnt(4)" ::: "memory");   // tile 0 fully landed
    BARR();

    for (int kt = 0; kt < KT8; ++kt) {
        const char* a0 = (const char*)&As[kt & 1][0][0];
        const char* a1 = (const char*)&As[kt & 1][1][0];
        const char* b0 = (const char*)&Bs[kt & 1][0][0];
        const char* b1 = (const char*)&Bs[kt & 1][1][0];

        // phase 1: (Ah0,Bh0) -> acc[0..3][0..1]; stage (kt+1).Bh0  [12 ds_read]
        LOAD_A(a0);
        LOAD_B(b0);
        if (kt + 1 < KT8) STAGE_B(kt + 1, 0);
        BARR(); LGKM0();
        MFMA16(0, 0);
        BARR();

        // phase 2: (Ah0,Bh1) -> acc[0..3][2..3]; stage (kt+1).Ah1  [4 ds_read]
        LOAD_B(b1);
        if (kt + 1 < KT8) STAGE_A(kt + 1, 1);
        BARR(); LGKM0();
        MFMA16(0, 2);
        BARR();

        // phase 3: (Ah1,Bh1) -> acc[4..7][2..3]; stage (kt+2).Ah0  [8 ds_read]
        // (tile kt's Ah0 slot: last ds_read was phase 1, completed at its
        //  lgkmcnt(0); two barriers ago -> WAR-safe)
        LOAD_A(a1);
        if (kt + 2 < KT8) STAGE_A(kt + 2, 0);
        BARR(); LGKM0();
        MFMA16(4, 2);
        BARR();

        // phase 4: (Ah1,Bh0) -> acc[4..7][0..1]; stage (kt+2).Bh1  [4 ds_read]
        LOAD_B(b0);
        if (kt + 2 < KT8) STAGE_B(kt + 2, 1);
        BARR(); LGKM0();
        MFMA16(4, 0);
        // counted wait: last 2 stages (tile kt+2's) stay in flight.
        // tail tiles issue fewer stages -> must drain fully.
        if (kt < KT8 - 2) asm volatile("s_waitcnt vmcnt(4)" ::: "memory");
        else              asm volatile("s_waitcnt vmcnt(0)" ::: "memory");
        BARR();
    }

#undef STAGE_A
#undef STAGE_B
#undef LOAD_A
#undef LOAD_B
#undef MFMA16
#undef BARR
#undef LGKM0

    // epilogue. C/D layout (probe-verified): n = lane&15, m = q*4 + reg.
    // acc[mf][nf]: row = m0 + (mf>>2)*128 + (mf&3)*32 + wm*16 + q*4 + r
    //              col = n0 + (nf>>1)*128 + (nf&1)*64 + wn*16 + lidx
    float bv[4];
    #pragma unroll
    for (int nf = 0; nf < 4; ++nf)
        bv[nf] = bias[n0 + (nf >> 1) * 128 + (nf & 1) * 64 + wn * 16 + lidx];

    if (f32w) {
        float* yf = (float*)yraw;
        #pragma unroll
        for (int mf = 0; mf < 8; ++mf)
            #pragma unroll
            for (int r = 0; r < 4; ++r) {
                const int m = m0 + (mf >> 2) * 128 + (mf & 3) * 32 + wm * 16 + q * 4 + r;
                float* yp = yf + (size_t)m * OUT_F + n0 + wn * 16 + lidx;
                #pragma unroll
                for (int nf = 0; nf < 4; ++nf)
                    yp[(nf >> 1) * 128 + (nf & 1) * 64] =
                        acc[mf][nf][r] * scale + bv[nf];
            }
    } else {
        __bf16* yh = (__bf16*)yraw;
        #pragma unroll
        for (int mf = 0; mf < 8; ++mf)
            #pragma unroll
            for (int r = 0; r < 4; ++r) {
                const int m = m0 + (mf >> 2) * 128 + (mf & 3) * 32 + wm * 16 + q * 4 + r;
                __bf16* yp = yh + (size_t)m * OUT_F + n0 + wn * 16 + lidx;
                #pragma unroll
                for (int nf = 0; nf < 4; ++nf)
                    yp[(nf >> 1) * 128 + (nf & 1) * 64] =
                        (__bf16)(acc[mf][nf][r] * scale + bv[nf]);
            }
    }
}

// ---- fallback (R6 kernel): only if ws_size can't hold cvt buffers ----
__global__ __launch_bounds__(256) void f8linear_fallback(
    const void*  __restrict__ xraw,
    const float* __restrict__ wq,
    const float* __restrict__ w_scale,
    const float* __restrict__ bias,
    void*        __restrict__ yraw,
    const int*   __restrict__ flag_p)
{
    __shared__ __align__(16) __bf16 As[BM * 40];
    __shared__ __align__(16) __bf16 Bs[BN * 40];

    const int f32w = (*flag_p != 0);
    const int t    = threadIdx.x;
    const int lane = t & 63;
    const int wv   = t >> 6;
    const int wm   = wv >> 1;
    const int wn   = wv & 1;
    const int lidx = lane & 15;
    const int q    = lane >> 4;

    const int flat = blockIdx.x;
    const int xcd  = flat & 7;
    const int slot = flat >> 3;
    const int ni   = xcd * 14 + (slot >> 3);
    const int mi   = slot & 7;
    const int m0   = mi * BM;
    const int n0   = ni * BN;

    const float scale = w_scale[0];
    const float*  xf = (const float*)xraw;
    const __bf16* xh = (const __bf16*)xraw;

    const int af_row = t >> 3;
    const int af_col = (t & 7) * 4;
    int ah_row[2], ah_cg[2];
    #pragma unroll
    for (int i = 0; i < 2; ++i) {
        const int s = i * 256 + t;
        ah_row[i] = s >> 2;
        ah_cg[i]  = s & 3;
    }
    const int b_row = t >> 3;
    const int b_col = (t & 7) * 4;

    const f32x4 zero4 = {0.f, 0.f, 0.f, 0.f};
    f32x4 acc[4][4];
    #pragma unroll
    for (int i = 0; i < 4; ++i)
        #pragma unroll
        for (int j = 0; j < 4; ++j)
            acc[i][j] = zero4;

    f32x4  aregf[4];
    bf16x8 aregh[2];
    f32x4  breg[4];
    if (f32w) {
        #pragma unroll
        for (int i = 0; i < 4; ++i)
            aregf[i] = *reinterpret_cast<const f32x4*>(
                xf + (size_t)(m0 + af_row + i * 32) * IN_F + af_col);
    } else {
        #pragma unroll
        for (int i = 0; i < 2; ++i)
            aregh[i] = *reinterpret_cast<const bf16x8*>(
                xh + (size_t)(m0 + ah_row[i]) * IN_F + ah_cg[i] * 8);
    }
    #pragma unroll
    for (int i = 0; i < 4; ++i)
        breg[i] = *reinterpret_cast<const f32x4*>(
            wq + (size_t)(n0 + i * 32 + b_row) * IN_F + b_col);

    for (int kt = 0; kt < 128; ++kt) {
        const int k0 = kt * 32;
        if (f32w) {
            #pragma unroll
            for (int i = 0; i < 4; ++i) {
                bf16x4 pk;
                pk[0] = (__bf16)aregf[i][0];
                pk[1] = (__bf16)aregf[i][1];
                pk[2] = (__bf16)aregf[i][2];
                pk[3] = (__bf16)aregf[i][3];
                *reinterpret_cast<bf16x4*>(As + (af_row + i * 32) * 40 + af_col) = pk;
            }
        } else {
            #pragma unroll
            for (int i = 0; i < 2; ++i)
                *reinterpret_cast<bf16x8*>(As + ah_row[i] * 40 + ah_cg[i] * 8) = aregh[i];
        }
        #pragma unroll
        for (int i = 0; i < 4; ++i) {
            bf16x4 pk;
            pk[0] = (__bf16)breg[i][0];
            pk[1] = (__bf16)breg[i][1];
            pk[2] = (__bf16)breg[i][2];
            pk[3] = (__bf16)breg[i][3];
            *reinterpret_cast<bf16x4*>(Bs + (i * 32 + b_row) * 40 + b_col) = pk;
        }
        __syncthreads();
        if (kt + 1 < 128) {
            const int k1 = k0 + 32;
            if (f32w) {
                #pragma unroll
                for (int i = 0; i < 4; ++i)
                    aregf[i] = *reinterpret_cast<const f32x4*>(
                        xf + (size_t)(m0 + af_row + i * 32) * IN_F + k1 + af_col);
            } else {
                #pragma unroll
                for (int i = 0; i < 2; ++i)
                    aregh[i] = *reinterpret_cast<const bf16x8*>(
                        xh + (size_t)(m0 + ah_row[i]) * IN_F + k1 + ah_cg[i] * 8);
            }
            #pragma unroll
            for (int i = 0; i < 4; ++i)
                breg[i] = *reinterpret_cast<const f32x4*>(
                    wq + (size_t)(n0 + i * 32 + b_row) * IN_F + k1 + b_col);
        }
        bf16x8 afr[4], bfr[4];
        #pragma unroll
        for (int mt = 0; mt < 4; ++mt) {
            const int row = wm * 64 + mt * 16 + lidx;
            afr[mt] = *reinterpret_cast<const bf16x8*>(As + row * 40 + q * 8);
        }
        #pragma unroll
        for (int nt = 0; nt < 4; ++nt) {
            const int row = wn * 64 + nt * 16 + lidx;
            bfr[nt] = *reinterpret_cast<const bf16x8*>(Bs + row * 40 + q * 8);
        }
        #pragma unroll
        for (int mt = 0; mt < 4; ++mt)
            #pragma unroll
            for (int nt = 0; nt < 4; ++nt)
                acc[mt][nt] = __builtin_amdgcn_mfma_f32_16x16x32_bf16(
                    afr[mt], bfr[nt], acc[mt][nt], 0, 0, 0);
        __syncthreads();
    }

    float bv[4];
    #pragma unroll
    for (int nt = 0; nt < 4; ++nt)
        bv[nt] = bias[n0 + wn * 64 + nt * 16 + lidx];

    if (f32w) {
        float* yf = (float*)yraw;
        #pragma unroll
        for (int mt = 0; mt < 4; ++mt)
            #pragma unroll
            for (int r = 0; r < 4; ++r) {
                const int m = m0 + wm * 64 + mt * 16 + q * 4 + r;
                float* yp = yf + (size_t)m * OUT_F + n0 + wn * 64 + lidx;
                #pragma unroll
                for (int nt = 0; nt < 4; ++nt)
                    yp[nt * 16] = acc[mt][nt][r] * scale + bv[nt];
            }
    } else {
        __bf16* yh = (__bf16*)yraw;
        #pragma unroll
        for (int mt = 0; mt < 4; ++mt)
            #pragma unroll
            for (int r = 0; r < 4; ++r) {
                const int m = m0 + wm * 64 + mt * 16 + q * 4 + r;
                __bf16* yp = yh + (size_t)m * OUT_F + n0 + wn * 64 + lidx;
                #pragma unroll
                for (int nt = 0; nt < 4; ++nt)
                    yp[nt * 16] = (__bf16)(acc[mt][nt][r] * scale + bv[nt]);
            }
    }
}

extern "C" void kernel_launch(void* const* d_in, const int* in_sizes, int n_in,
                              void* d_out, int out_size, void* d_ws, size_t ws_size,
                              hipStream_t stream) {
    const void* px = nullptr; const void* pw = nullptr;
    const void* ps = nullptr; const void* pb = nullptr;
    for (int i = 0; i < n_in; ++i) {
        const long sz = in_sizes[i];
        if      (sz == (long)M_TOT * IN_F) px = d_in[i];
        else if (sz == (long)OUT_F * IN_F) pw = d_in[i];
        else if (sz == 1)                  ps = d_in[i];
        else if (sz == OUT_F)              pb = d_in[i];
    }
    if (!px) px = d_in[0];
    if (!pw) pw = d_in[1];
    if (!ps) ps = d_in[2];
    if (!pb) pb = d_in[3];

    const size_t W_BYTES  = (size_t)OUT_F * IN_F * 2;   // 117,440,512
    const size_t X_OFF    = W_BYTES;
    const size_t X_BYTES  = (size_t)M_TOT * IN_F * 2;   // 8,388,608
    const size_t FLAG_OFF = X_OFF + X_BYTES;            // 125,829,120

    if (ws_size >= FLAG_OFF + 16) {
        __bf16* wbf  = (__bf16*)d_ws;
        __bf16* xbf  = (__bf16*)((char*)d_ws + X_OFF);
        int*    flag = (int*)((char*)d_ws + FLAG_OFF);

        const int grid8 = (M_TOT / TM) * (OUT_F / TN);  // 224

        detect_x_dtype<<<1, 256, 0, stream>>>((const uint32_t*)px, flag);
        cvt_w_kernel<<<3584, 256, 0, stream>>>((const f32x4*)pw, (bf16x8*)wbf);
        cvt_x_kernel<<<2048, 256, 0, stream>>>(px, (bf16x8*)xbf, flag);
        gemm_bf16_8ph<<<grid8, 512, 0, stream>>>(
            xbf, wbf, (const float*)ps, (const float*)pb, d_out, flag);
    } else {
        int* flag = (int*)d_ws;
        const int grid = (M_TOT / BM) * (OUT_F / BN);   // 896
        detect_x_dtype<<<1, 256, 0, stream>>>((const uint32_t*)px, flag);
        f8linear_fallback<<<grid, 256, 0, stream>>>(
            px, (const float*)pw, (const float*)ps, (const float*)pb, d_out, flag);
    }
}

// Round 2
// 506.367 us; speedup vs baseline: 1.0594x; 1.0433x over previous
//
#include <hip/hip_runtime.h>
#include <hip/hip_bf16.h>
#include <stdint.h>

// F8Linear: y[m,n] = sum_k x[m,k] * (w_f8[n,k] * s) + bias[n]
// M=1024, N=14336, K=4096.
// R10: cvt_w ELIMINATED — f32->bf16 W conversion fused into GEMM staging.
//   B operand reg-staged (global f32x4 loads -> in-reg cvt -> swizzled
//   ds_write_b128), T14 async-split across phases with exact counted
//   vmcnt (ph3: 6, ph4: 4/2, tile-end: 2/0). A operand unchanged
//   (global_load_lds from cvt_x'd bf16 buffer). 8-phase 256x256 schedule,
//   XOR-16B-group swizzle, raw s_barrier + lgkmcnt(0)+sched_barrier,
//   setprio around MFMA clusters — all unchanged from R9.
// R9 post-mortem: 8-phase gave ZERO GEMM delta (186->184 us, MfmaUtil
//   flat 26%) — schedule is not the limiting term; ~330 us of total 528
//   was cvt_w + overhead. This round removes that term.

#define IN_F   4096
#define OUT_F  14336
#define M_TOT  1024

// legacy fallback tile params
#define BM 128
#define BN 128

// 8-phase kernel params
#define TM 256
#define TN 256
#define TK 64
#define KT8 (IN_F / TK)   // 64

typedef __bf16  bf16x8 __attribute__((ext_vector_type(8)));
typedef __bf16  bf16x4 __attribute__((ext_vector_type(4)));
typedef float   f32x4  __attribute__((ext_vector_type(4)));

__device__ __forceinline__ void async_copy16(const void* g, void* l) {
    __builtin_amdgcn_global_load_lds(
        (const __attribute__((address_space(1))) void*)g,
        (__attribute__((address_space(3))) void*)l,
        16, 0, 0);
}

// ---- detector: bf16-valued f32 words have low16 == 0 over 1024 dwords ----
__global__ void detect_x_dtype(const uint32_t* __restrict__ xb,
                               int* __restrict__ flag) {
    __shared__ int any_low;
    if (threadIdx.x == 0) any_low = 0;
    __syncthreads();
    uint32_t bad = 0;
    for (int i = threadIdx.x; i < 1024; i += 256) bad |= (xb[i] & 0xFFFFu);
    if (bad) atomicOr(&any_low, 1);
    __syncthreads();
    if (threadIdx.x == 0) *flag = (any_low == 0) ? 1 : 0;
}

// ---- cvt_x: 4,194,304 elems -> bf16 (cvt f32-world, copy bf16-world) ----
__global__ __launch_bounds__(256) void cvt_x_kernel(
    const void* __restrict__ xraw, bf16x8* __restrict__ out,
    const int* __restrict__ flag) {
    const int f32w = (*flag != 0);
    const int i = blockIdx.x * 256 + threadIdx.x;   // 0..524287
    if (f32w) {
        const f32x4* in = (const f32x4*)xraw;
        f32x4 a = in[2 * i];
        f32x4 b = in[2 * i + 1];
        bf16x8 o;
        o[0] = (__bf16)a[0]; o[1] = (__bf16)a[1];
        o[2] = (__bf16)a[2]; o[3] = (__bf16)a[3];
        o[4] = (__bf16)b[0]; o[5] = (__bf16)b[1];
        o[6] = (__bf16)b[2]; o[7] = (__bf16)b[3];
        out[i] = o;
    } else {
        out[i] = ((const bf16x8*)xraw)[i];
    }
}

// ---- main GEMM: 256x256 tile, 8-phase, fused f32->bf16 B staging ----
__global__ __launch_bounds__(512, 2) void gemm_fused_8ph(
    const __bf16* __restrict__ xb,     // [M_TOT][IN_F] bf16 (ws)
    const float*  __restrict__ wf,     // [OUT_F][IN_F] f32 (original input!)
    const float*  __restrict__ w_scale,
    const float*  __restrict__ bias,
    void*         __restrict__ yraw,   // f32 or bf16 container per flag
    const int*    __restrict__ flag_p)
{
    // [dbuf][half]: half = 128 rows x 64 cols bf16 = 16 KiB. Total 128 KiB.
    __shared__ __align__(16) __bf16 As[2][2][128 * TK];
    __shared__ __align__(16) __bf16 Bs[2][2][128 * TK];

    const int f32w = (*flag_p != 0);
    const int t    = threadIdx.x;
    const int lane = t & 63;
    const int wv   = t >> 6;     // 0..7
    const int wm   = wv >> 2;    // 0..1
    const int wn   = wv & 3;     // 0..3
    const int lidx = lane & 15;
    const int q    = lane >> 4;

    // 224 blocks = 8 XCDs x 28; per XCD: 7 N-panels x 4 M-tiles (M fastest)
    const int flat = blockIdx.x;
    const int xcd  = flat & 7;
    const int slot = flat >> 3;            // 0..27
    const int ni   = xcd * 7 + (slot >> 2);
    const int mi   = slot & 3;
    const int m0   = mi * TM;
    const int n0   = ni * TN;

    const float scale = w_scale[0];

    const __bf16* gA = xb + (size_t)m0 * IN_F;

    // staging geometry: half-tile = 1024 slots of 8 bf16; 512 threads x 2.
    // slot s -> row = s>>3, phys 16B-group = s&7 holds LOGICAL group
    // (s&7)^(row&7)  (conflict-free swizzle; LDS dest stays linear).
    int srow[2], scgl[2];
    #pragma unroll
    for (int i = 0; i < 2; ++i) {
        const int s = i * 512 + t;
        srow[i] = s >> 3;
        scgl[i] = (s & 7) ^ (srow[i] & 7);
    }

    // B source (f32): per-thread bases for the two slots
    const float* gB0 = wf + (size_t)(n0 + srow[0]) * IN_F + scgl[0] * 8;
    const float* gB1 = wf + (size_t)(n0 + srow[1]) * IN_F + scgl[1] * 8;

    // ds_read byte offsets within one half-buffer (row*128B + physgrp*16B).
    int aoff[4][2], boff[2][2];
    #pragma unroll
    for (int qm = 0; qm < 4; ++qm) {
        const int row = qm * 32 + wm * 16 + lidx;
        #pragma unroll
        for (int kg = 0; kg < 2; ++kg)
            aoff[qm][kg] = row * 128 + (((kg * 4 + q) ^ (row & 7)) * 16);
    }
    #pragma unroll
    for (int qn = 0; qn < 2; ++qn) {
        const int row = qn * 64 + wn * 16 + lidx;
        #pragma unroll
        for (int kg = 0; kg < 2; ++kg)
            boff[qn][kg] = row * 128 + (((kg * 4 + q) ^ (row & 7)) * 16);
    }

    const f32x4 zero4 = {0.f, 0.f, 0.f, 0.f};
    f32x4 acc[8][4];
    #pragma unroll
    for (int i = 0; i < 8; ++i)
        #pragma unroll
        for (int j = 0; j < 4; ++j)
            acc[i][j] = zero4;

    bf16x8 areg[4][2], breg[2][2];
    f32x4  Br0[4], Br1[4];   // in-flight B staging regs (static-indexed)

#define STAGE_A(tile, half) do {                                              \
    __bf16* _dst = &As[(tile) & 1][(half)][0];                                \
    const __bf16* _src = gA + (size_t)(half) * 128 * IN_F + (tile) * TK;      \
    async_copy16(_src + (size_t)srow[0] * IN_F + scgl[0] * 8, _dst + t * 8);  \
    async_copy16(_src + (size_t)srow[1] * IN_F + scgl[1] * 8,                 \
                 _dst + (512 + t) * 8);                                       \
} while (0)

// issue 4 global f32x4 loads (2 slots x 2) for half-tile (tile,half) of B
#define B_LOAD(tile, half, Rv) do {                                           \
    const float* _p0 = gB0 + (size_t)(half) * 128 * IN_F + (tile) * TK;       \
    const float* _p1 = gB1 + (size_t)(half) * 128 * IN_F + (tile) * TK;       \
    Rv[0] = *(const f32x4*)_p0;                                               \
    Rv[1] = *(const f32x4*)(_p0 + 4);                                         \
    Rv[2] = *(const f32x4*)_p1;                                               \
    Rv[3] = *(const f32x4*)(_p1 + 4);                                         \
} while (0)

// cvt + swizzled ds_write of the staged half-tile (dest linear in slot id)
#define B_WRITE(tile, half, Rv) do {                                          \
    __bf16* _d = &Bs[(tile) & 1][(half)][0];                                  \
    bf16x8 _o;                                                                \
    _o[0] = (__bf16)Rv[0][0]; _o[1] = (__bf16)Rv[0][1];                       \
    _o[2] = (__bf16)Rv[0][2]; _o[3] = (__bf16)Rv[0][3];                       \
    _o[4] = (__bf16)Rv[1][0]; _o[5] = (__bf16)Rv[1][1];                       \
    _o[6] = (__bf16)Rv[1][2]; _o[7] = (__bf16)Rv[1][3];                       \
    *(bf16x8*)(_d + (size_t)t * 8) = _o;                                      \
    _o[0] = (__bf16)Rv[2][0]; _o[1] = (__bf16)Rv[2][1];                       \
    _o[2] = (__bf16)Rv[2][2]; _o[3] = (__bf16)Rv[2][3];                       \
    _o[4] = (__bf16)Rv[3][0]; _o[5] = (__bf16)Rv[3][1];                       \
    _o[6] = (__bf16)Rv[3][2]; _o[7] = (__bf16)Rv[3][3];                       \
    *(bf16x8*)(_d + (size_t)(512 + t) * 8) = _o;                              \
} while (0)

#define LOAD_A(base) do {                                                     \
    _Pragma("unroll")                                                         \
    for (int _qm = 0; _qm < 4; ++_qm) {                                       \
        areg[_qm][0] = *(const bf16x8*)((base) + aoff[_qm][0]);               \
        areg[_qm][1] = *(const bf16x8*)((base) + aoff[_qm][1]);               \
    }                                                                         \
} while (0)

#define LOAD_B(base) do {                                                     \
    _Pragma("unroll")                                                         \
    for (int _qn = 0; _qn < 2; ++_qn) {                                       \
        breg[_qn][0] = *(const bf16x8*)((base) + boff[_qn][0]);               \
        breg[_qn][1] = *(const bf16x8*)((base) + boff[_qn][1]);               \
    }                                                                         \
} while (0)

#define MFMA16(MO, NO) do {                                                   \
    __builtin_amdgcn_s_setprio(1);                                            \
    _Pragma("unroll")                                                         \
    for (int _qm = 0; _qm < 4; ++_qm)                                         \
        _Pragma("unroll")                                                     \
        for (int _qn = 0; _qn < 2; ++_qn) {                                   \
            acc[(MO) + _qm][(NO) + _qn] =                                     \
                __builtin_amdgcn_mfma_f32_16x16x32_bf16(                      \
                    areg[_qm][0], breg[_qn][0], acc[(MO) + _qm][(NO) + _qn],  \
                    0, 0, 0);                                                 \
            acc[(MO) + _qm][(NO) + _qn] =                                     \
                __builtin_amdgcn_mfma_f32_16x16x32_bf16(                      \
                    areg[_qm][1], breg[_qn][1], acc[(MO) + _qm][(NO) + _qn],  \
                    0, 0, 0);                                                 \
        }                                                                     \
    __builtin_amdgcn_s_setprio(0);                                            \
} while (0)

#define BARR() __builtin_amdgcn_s_barrier()
#define LGKM0() do {                                                          \
    asm volatile("s_waitcnt lgkmcnt(0)" ::: "memory");                        \
    __builtin_amdgcn_sched_barrier(0);                                        \
} while (0)
#define VMCNT(n) asm volatile("s_waitcnt vmcnt(" #n ")" ::: "memory")

    // ---- prologue ----
    // issue order: Br0(4), Br1(4), A(0,0)(2), A(0,1)(2), A(1,0)(2) = 14 ops
    B_LOAD(0, 0, Br0);
    B_LOAD(0, 1, Br1);
    STAGE_A(0, 0);
    STAGE_A(0, 1);
    STAGE_A(1, 0);
    VMCNT(6);            // Br0+Br1 landed (A-dmas 6 in flight)
    B_WRITE(0, 0, Br0);
    B_WRITE(0, 1, Br1);
    VMCNT(2);            // A(0,*) landed; A(1,0) stays in flight
    LGKM0();             // own ds_writes complete before barrier
    BARR();

    // steady-state invariant at tile kt entry:
    //   LDS: tile kt fully resident. vmem outstanding: A(kt+1,h0) x2.
    for (int kt = 0; kt < KT8; ++kt) {
        const char* a0 = (const char*)&As[kt & 1][0][0];
        const char* a1 = (const char*)&As[kt & 1][1][0];
        const char* b0 = (const char*)&Bs[kt & 1][0][0];
        const char* b1 = (const char*)&Bs[kt & 1][1][0];

        // phase 1: (Ah0,Bh0) -> acc[0..3][0..1]; issue B(kt+1,h0) loads
        LOAD_A(a0);
        LOAD_B(b0);
        if (kt + 1 < KT8) B_LOAD(kt + 1, 0, Br0);
        BARR(); LGKM0();
        MFMA16(0, 0);
        BARR();

        // phase 2: (Ah0,Bh1) -> acc[0..3][2..3]; issue B(kt+1,h1) + A(kt+1,h1)
        LOAD_B(b1);
        if (kt + 1 < KT8) {
            B_LOAD(kt + 1, 1, Br1);
            STAGE_A(kt + 1, 1);
        }
        BARR(); LGKM0();
        MFMA16(0, 2);
        BARR();

        // phase 3: (Ah1,Bh1) -> acc[4..7][2..3];
        //   write B(kt+1,h0) (outstanding after Br0: Br1 4 + A(kt+1,h1) 2 = 6),
        //   then issue A(kt+2,h0). WAR on Bs[(kt+1)&1][0]: last read was
        //   tile kt-1 ph4, >=3 barriers ago.
        LOAD_A(a1);
        if (kt + 1 < KT8) {
            VMCNT(6);
            B_WRITE(kt + 1, 0, Br0);
        }
        if (kt + 2 < KT8) STAGE_A(kt + 2, 0);
        BARR(); LGKM0();
        MFMA16(4, 2);
        BARR();

        // phase 4: (Ah1,Bh0) -> acc[4..7][0..1];
        //   write B(kt+1,h1) (after Br1: A(kt+1,h1) 2 [+ A(kt+2,h0) 2]).
        LOAD_B(b0);
        if (kt + 1 < KT8) {
            if (kt + 2 < KT8) { VMCNT(4); } else { VMCNT(2); }
            B_WRITE(kt + 1, 1, Br1);
        }
        BARR(); LGKM0();
        MFMA16(4, 0);
        // tile-end: A(kt+1,h1) must land; leave A(kt+2,h0) in flight.
        if (kt + 1 < KT8) {
            if (kt + 2 < KT8) { VMCNT(2); } else { VMCNT(0); }
        }
        BARR();
    }

#undef STAGE_A
#undef B_LOAD
#undef B_WRITE
#undef LOAD_A
#undef LOAD_B
#undef MFMA16
#undef BARR
#undef LGKM0
#undef VMCNT

    // epilogue. C/D layout (probe-verified): n = lane&15, m = q*4 + reg.
    // acc[mf][nf]: row = m0 + (mf>>2)*128 + (mf&3)*32 + wm*16 + q*4 + r
    //              col = n0 + (nf>>1)*128 + (nf&1)*64 + wn*16 + lidx
    float bv[4];
    #pragma unroll
    for (int nf = 0; nf < 4; ++nf)
        bv[nf] = bias[n0 + (nf >> 1) * 128 + (nf & 1) * 64 + wn * 16 + lidx];

    if (f32w) {
        float* yf = (float*)yraw;
        #pragma unroll
        for (int mf = 0; mf < 8; ++mf)
            #pragma unroll
            for (int r = 0; r < 4; ++r) {
                const int m = m0 + (mf >> 2) * 128 + (mf & 3) * 32 + wm * 16 + q * 4 + r;
                float* yp = yf + (size_t)m * OUT_F + n0 + wn * 16 + lidx;
                #pragma unroll
                for (int nf = 0; nf < 4; ++nf)
                    yp[(nf >> 1) * 128 + (nf & 1) * 64] =
                        acc[mf][nf][r] * scale + bv[nf];
            }
    } else {
        __bf16* yh = (__bf16*)yraw;
        #pragma unroll
        for (int mf = 0; mf < 8; ++mf)
            #pragma unroll
            for (int r = 0; r < 4; ++r) {
                const int m = m0 + (mf >> 2) * 128 + (mf & 3) * 32 + wm * 16 + q * 4 + r;
                __bf16* yp = yh + (size_t)m * OUT_F + n0 + wn * 16 + lidx;
                #pragma unroll
                for (int nf = 0; nf < 4; ++nf)
                    yp[(nf >> 1) * 128 + (nf & 1) * 64] =
                        (__bf16)(acc[mf][nf][r] * scale + bv[nf]);
            }
    }
}

// ---- fallback (R6 kernel): only if ws_size can't hold cvt_x buffer ----
__global__ __launch_bounds__(256) void f8linear_fallback(
    const void*  __restrict__ xraw,
    const float* __restrict__ wq,
    const float* __restrict__ w_scale,
    const float* __restrict__ bias,
    void*        __restrict__ yraw,
    const int*   __restrict__ flag_p)
{
    __shared__ __align__(16) __bf16 As[BM * 40];
    __shared__ __align__(16) __bf16 Bs[BN * 40];

    const int f32w = (*flag_p != 0);
    const int t    = threadIdx.x;
    const int lane = t & 63;
    const int wv   = t >> 6;
    const int wm   = wv >> 1;
    const int wn   = wv & 1;
    const int lidx = lane & 15;
    const int q    = lane >> 4;

    const int flat = blockIdx.x;
    const int xcd  = flat & 7;
    const int slot = flat >> 3;
    const int ni   = xcd * 14 + (slot >> 3);
    const int mi   = slot & 7;
    const int m0   = mi * BM;
    const int n0   = ni * BN;

    const float scale = w_scale[0];
    const float*  xf = (const float*)xraw;
    const __bf16* xh = (const __bf16*)xraw;

    const int af_row = t >> 3;
    const int af_col = (t & 7) * 4;
    int ah_row[2], ah_cg[2];
    #pragma unroll
    for (int i = 0; i < 2; ++i) {
        const int s = i * 256 + t;
        ah_row[i] = s >> 2;
        ah_cg[i]  = s & 3;
    }
    const int b_row = t >> 3;
    const int b_col = (t & 7) * 4;

    const f32x4 zero4 = {0.f, 0.f, 0.f, 0.f};
    f32x4 acc[4][4];
    #pragma unroll
    for (int i = 0; i < 4; ++i)
        #pragma unroll
        for (int j = 0; j < 4; ++j)
            acc[i][j] = zero4;

    f32x4  aregf[4];
    bf16x8 aregh[2];
    f32x4  breg[4];
    if (f32w) {
        #pragma unroll
        for (int i = 0; i < 4; ++i)
            aregf[i] = *reinterpret_cast<const f32x4*>(
                xf + (size_t)(m0 + af_row + i * 32) * IN_F + af_col);
    } else {
        #pragma unroll
        for (int i = 0; i < 2; ++i)
            aregh[i] = *reinterpret_cast<const bf16x8*>(
                xh + (size_t)(m0 + ah_row[i]) * IN_F + ah_cg[i] * 8);
    }
    #pragma unroll
    for (int i = 0; i < 4; ++i)
        breg[i] = *reinterpret_cast<const f32x4*>(
            wq + (size_t)(n0 + i * 32 + b_row) * IN_F + b_col);

    for (int kt = 0; kt < 128; ++kt) {
        const int k0 = kt * 32;
        if (f32w) {
            #pragma unroll
            for (int i = 0; i < 4; ++i) {
                bf16x4 pk;
                pk[0] = (__bf16)aregf[i][0];
                pk[1] = (__bf16)aregf[i][1];
                pk[2] = (__bf16)aregf[i][2];
                pk[3] = (__bf16)aregf[i][3];
                *reinterpret_cast<bf16x4*>(As + (af_row + i * 32) * 40 + af_col) = pk;
            }
        } else {
            #pragma unroll
            for (int i = 0; i < 2; ++i)
                *reinterpret_cast<bf16x8*>(As + ah_row[i] * 40 + ah_cg[i] * 8) = aregh[i];
        }
        #pragma unroll
        for (int i = 0; i < 4; ++i) {
            bf16x4 pk;
            pk[0] = (__bf16)breg[i][0];
            pk[1] = (__bf16)breg[i][1];
            pk[2] = (__bf16)breg[i][2];
            pk[3] = (__bf16)breg[i][3];
            *reinterpret_cast<bf16x4*>(Bs + (i * 32 + b_row) * 40 + b_col) = pk;
        }
        __syncthreads();
        if (kt + 1 < 128) {
            const int k1 = k0 + 32;
            if (f32w) {
                #pragma unroll
                for (int i = 0; i < 4; ++i)
                    aregf[i] = *reinterpret_cast<const f32x4*>(
                        xf + (size_t)(m0 + af_row + i * 32) * IN_F + k1 + af_col);
            } else {
                #pragma unroll
                for (int i = 0; i < 2; ++i)
                    aregh[i] = *reinterpret_cast<const bf16x8*>(
                        xh + (size_t)(m0 + ah_row[i]) * IN_F + k1 + ah_cg[i] * 8);
            }
            #pragma unroll
            for (int i = 0; i < 4; ++i)
                breg[i] = *reinterpret_cast<const f32x4*>(
                    wq + (size_t)(n0 + i * 32 + b_row) * IN_F + k1 + b_col);
        }
        bf16x8 afr[4], bfr[4];
        #pragma unroll
        for (int mt = 0; mt < 4; ++mt) {
            const int row = wm * 64 + mt * 16 + lidx;
            afr[mt] = *reinterpret_cast<const bf16x8*>(As + row * 40 + q * 8);
        }
        #pragma unroll
        for (int nt = 0; nt < 4; ++nt) {
            const int row = wn * 64 + nt * 16 + lidx;
            bfr[nt] = *reinterpret_cast<const bf16x8*>(Bs + row * 40 + q * 8);
        }
        #pragma unroll
        for (int mt = 0; mt < 4; ++mt)
            #pragma unroll
            for (int nt = 0; nt < 4; ++nt)
                acc[mt][nt] = __builtin_amdgcn_mfma_f32_16x16x32_bf16(
                    afr[mt], bfr[nt], acc[mt][nt], 0, 0, 0);
        __syncthreads();
    }

    float bv[4];
    #pragma unroll
    for (int nt = 0; nt < 4; ++nt)
        bv[nt] = bias[n0 + wn * 64 + nt * 16 + lidx];

    if (f32w) {
        float* yf = (float*)yraw;
        #pragma unroll
        for (int mt = 0; mt < 4; ++mt)
            #pragma unroll
            for (int r = 0; r < 4; ++r) {
                const int m = m0 + wm * 64 + mt * 16 + q * 4 + r;
                float* yp = yf + (size_t)m * OUT_F + n0 + wn * 64 + lidx;
                #pragma unroll
                for (int nt = 0; nt < 4; ++nt)
                    yp[nt * 16] = acc[mt][nt][r] * scale + bv[nt];
            }
    } else {
        __bf16* yh = (__bf16*)yraw;
        #pragma unroll
        for (int mt = 0; mt < 4; ++mt)
            #pragma unroll
            for (int r = 0; r < 4; ++r) {
                const int m = m0 + wm * 64 + mt * 16 + q * 4 + r;
                __bf16* yp = yh + (size_t)m * OUT_F + n0 + wn * 64 + lidx;
                #pragma unroll
                for (int nt = 0; nt < 4; ++nt)
                    yp[nt * 16] = (__bf16)(acc[mt][nt][r] * scale + bv[nt]);
            }
    }
}

extern "C" void kernel_launch(void* const* d_in, const int* in_sizes, int n_in,
                              void* d_out, int out_size, void* d_ws, size_t ws_size,
                              hipStream_t stream) {
    const void* px = nullptr; const void* pw = nullptr;
    const void* ps = nullptr; const void* pb = nullptr;
    for (int i = 0; i < n_in; ++i) {
        const long sz = in_sizes[i];
        if      (sz == (long)M_TOT * IN_F) px = d_in[i];
        else if (sz == (long)OUT_F * IN_F) pw = d_in[i];
        else if (sz == 1)                  ps = d_in[i];
        else if (sz == OUT_F)              pb = d_in[i];
    }
    if (!px) px = d_in[0];
    if (!pw) pw = d_in[1];
    if (!ps) ps = d_in[2];
    if (!pb) pb = d_in[3];

    const size_t X_BYTES  = (size_t)M_TOT * IN_F * 2;   // 8,388,608
    const size_t FLAG_OFF = X_BYTES;

    if (ws_size >= FLAG_OFF + 16) {
        __bf16* xbf  = (__bf16*)d_ws;
        int*    flag = (int*)((char*)d_ws + FLAG_OFF);

        const int grid8 = (M_TOT / TM) * (OUT_F / TN);  // 224

        detect_x_dtype<<<1, 256, 0, stream>>>((const uint32_t*)px, flag);
        cvt_x_kernel<<<2048, 256, 0, stream>>>(px, (bf16x8*)xbf, flag);
        gemm_fused_8ph<<<grid8, 512, 0, stream>>>(
            xbf, (const float*)pw, (const float*)ps, (const float*)pb,
            d_out, flag);
    } else {
        int* flag = (int*)d_ws;
        const int grid = (M_TOT / BM) * (OUT_F / BN);   // 896
        detect_x_dtype<<<1, 256, 0, stream>>>((const uint32_t*)px, flag);
        f8linear_fallback<<<grid, 256, 0, stream>>>(
            px, (const float*)pw, (const float*)ps, (const float*)pb, d_out, flag);
    }
}